// Round 4
// baseline (146.273 us; speedup 1.0000x reference)
//
#include <hip/hip_runtime.h>
#include <math.h>
#include <stdint.h>

#define T_SEQ 2048
#define BATCH 4
#define DMODEL 128
#define DFF 512
#define NHEAD 8
#define EHEAD 16

#define RSQRT_T 0.022097086912079608f
#define QSCALE (0.022097086912079608f * 1.4426950408889634f)   // fold log2(e): use exp2

typedef __attribute__((ext_vector_type(8))) short bf16x8;
typedef __attribute__((ext_vector_type(4))) short bf16x4;
typedef __attribute__((ext_vector_type(4))) float f32x4;

__device__ __forceinline__ short f2bf(float f) {            // RNE
    uint32_t u = __float_as_uint(f);
    u = u + 0x7FFF + ((u >> 16) & 1);
    return (short)(u >> 16);
}
__device__ __forceinline__ short bftrunc(float f) {         // truncate (cheap)
    return (short)(__float_as_uint(f) >> 16);
}
__device__ __forceinline__ float bf2f(short s) {
    return __uint_as_float(((uint32_t)(unsigned short)s) << 16);
}

// ---------------------------------------------------------------------------
// K0: xpe = x + PE (fp32 + bf16 copies); transpose+convert all weights to bf16
// ---------------------------------------------------------------------------
__global__ __launch_bounds__(256) void k_pre(const float* __restrict__ x,
                                             const float* __restrict__ WQ,
                                             const float* __restrict__ WK,
                                             const float* __restrict__ WV,
                                             const float* __restrict__ W1,
                                             const float* __restrict__ W2,
                                             float* __restrict__ xpe,
                                             short* __restrict__ xpe16,
                                             short* __restrict__ Wqkvt,
                                             short* __restrict__ W1t,
                                             short* __restrict__ W2t) {
    int bid = blockIdx.x;
    int tid = threadIdx.x;
    if (bid < 4096) {                       // PE over B*T*D = 1M
        int idx = bid * 256 + tid;
        int f = idx & (DMODEL - 1);
        int t = (idx >> 7) & (T_SEQ - 1);
        float dv = __expf(-(float)(f & ~1) * (9.210340371976184f / 128.0f));
        float ang = (float)t * dv;
        float pe = (f & 1) ? __cosf(ang) : __sinf(ang);
        float v = x[idx] + pe;
        xpe[idx] = v;
        xpe16[idx] = f2bf(v);
    } else if (bid < 4288) {                // WQ/WK/WV -> [n][k] bf16
        int m = (bid - 4096) >> 6;
        int o = ((bid - 4096) & 63) * 256 + tid;      // 0..16383
        int n = o >> 7, k = o & 127;
        const float* W = (m == 0) ? WQ : (m == 1) ? WK : WV;
        Wqkvt[m * 16384 + o] = f2bf(W[k * 128 + n]);
    } else if (bid < 4544) {                // W1 [128][512] -> W1t [512][128]
        int o = (bid - 4288) * 256 + tid;   // 0..65535
        int n = o >> 7, k = o & 127;
        W1t[o] = f2bf(W1[k * 512 + n]);
    } else {                                // W2 [512][128] -> W2t [128][512]
        int o = (bid - 4544) * 256 + tid;   // 0..65535
        int n = o >> 9, k = o & 511;
        W2t[o] = f2bf(W2[k * 128 + n]);
    }
}

// ---------------------------------------------------------------------------
// K1: QKV projection: bf16 MFMA GEMM, W in registers (Wt[n][k] bf16).
// z=0: Qh[hb][t][16] *= QSCALE; z=1: Kh[hb][t][16]; z=2: Vs[hb][e][T]
// block 256 (4 waves x 16 rows = 64 rows), grid (128, 3)
// ---------------------------------------------------------------------------
__global__ __launch_bounds__(256) void k_qkv(const short* __restrict__ xpe16,
                                             const short* __restrict__ Wqkvt,
                                             short* __restrict__ Qh,
                                             short* __restrict__ Kh,
                                             short* __restrict__ Vs) {
    int z = blockIdx.y;
    const short* Wt = Wqkvt + z * 16384;
    int wave = threadIdx.x >> 6, lane = threadIdx.x & 63;
    int g = lane >> 4, c = lane & 15;
    int row0 = blockIdx.x * 64 + wave * 16;

    bf16x8 wf[8][4];
#pragma unroll
    for (int nt = 0; nt < 8; ++nt)
#pragma unroll
        for (int kk = 0; kk < 4; ++kk)
            wf[nt][kk] = *(const bf16x8*)(Wt + (nt * 16 + c) * 128 + kk * 32 + 8 * g);

    bf16x8 af[4];
#pragma unroll
    for (int kk = 0; kk < 4; ++kk)
        af[kk] = *(const bf16x8*)(xpe16 + (size_t)(row0 + c) * 128 + kk * 32 + 8 * g);

    f32x4 acc[8];
#pragma unroll
    for (int nt = 0; nt < 8; ++nt) acc[nt] = (f32x4){0.f, 0.f, 0.f, 0.f};
#pragma unroll
    for (int kk = 0; kk < 4; ++kk)
#pragma unroll
        for (int nt = 0; nt < 8; ++nt)
            acc[nt] = __builtin_amdgcn_mfma_f32_16x16x32_bf16(af[kk], wf[nt][kk], acc[nt], 0, 0, 0);

    int b = row0 >> 11;
    int t0 = (row0 & (T_SEQ - 1)) + 4 * g;
    if (z < 2) {
        short* dst = (z == 0) ? Qh : Kh;
        float sc = (z == 0) ? QSCALE : 1.0f;
#pragma unroll
        for (int nt = 0; nt < 8; ++nt) {
            int hb = nt * 4 + b;
#pragma unroll
            for (int r = 0; r < 4; ++r)
                dst[(size_t)(hb * T_SEQ + t0 + r) * 16 + c] = f2bf(acc[nt][r] * sc);
        }
    } else {
#pragma unroll
        for (int nt = 0; nt < 8; ++nt) {
            int hb = nt * 4 + b;
            bf16x4 v;
#pragma unroll
            for (int r = 0; r < 4; ++r) v[r] = f2bf(acc[nt][r]);
            *(bf16x4*)(Vs + (size_t)(hb * 16 + c) * T_SEQ + t0) = v;
        }
    }
}

// ---------------------------------------------------------------------------
// K2: column-softmax denominators + pre-scale V in place. Wave-independent:
// each wave owns 32 k-columns (2 K-frags in regs), streams Q tiles from L2.
// Vs[hb][e][k] *= 1 / sum_{q>=k} exp2(S'[q,k])
// grid (16, 32 hb), block 256 = 4 waves; slot s = bx*4+wave, k0 = s*32
// (s=0 is the longest -> dispatched first)
// ---------------------------------------------------------------------------
__global__ __launch_bounds__(256) void k_colsum(const short* __restrict__ Qh,
                                                const short* __restrict__ Kh,
                                                short* __restrict__ Vs) {
    __shared__ float invl[4][32];
    int hb = blockIdx.y;
    int wave = threadIdx.x >> 6, lane = threadIdx.x & 63;
    int g = lane >> 4, c = lane & 15;
    int s = blockIdx.x * 4 + wave;
    int k0 = s * 32;
    const int hbT = hb * T_SEQ;
    const f32x4 z = {0.f, 0.f, 0.f, 0.f};

    bf16x8 kfA = {0, 0, 0, 0, 0, 0, 0, 0};
    bf16x8 kfB = {0, 0, 0, 0, 0, 0, 0, 0};
    if (g < 2) {
        kfA = *(const bf16x8*)(Kh + (size_t)(hbT + k0 + c) * 16 + 8 * g);
        kfB = *(const bf16x8*)(Kh + (size_t)(hbT + k0 + 16 + c) * 16 + 8 * g);
    }

    float csA = 0.f, csB = 0.f;
    {   // q-tile at k0: A diagonal, B all-masked (k > q)
        bf16x8 qf = {0, 0, 0, 0, 0, 0, 0, 0};
        if (g < 2) qf = *(const bf16x8*)(Qh + (size_t)(hbT + k0 + c) * 16 + 8 * g);
        f32x4 sA = __builtin_amdgcn_mfma_f32_16x16x32_bf16(qf, kfA, z, 0, 0, 0);
#pragma unroll
        for (int r = 0; r < 4; ++r)
            csA += (4 * g + r >= c) ? exp2f(sA[r]) : 0.f;
    }
    {   // q-tile at k0+16: A full, B diagonal
        bf16x8 qf = {0, 0, 0, 0, 0, 0, 0, 0};
        if (g < 2) qf = *(const bf16x8*)(Qh + (size_t)(hbT + k0 + 16 + c) * 16 + 8 * g);
        f32x4 sA = __builtin_amdgcn_mfma_f32_16x16x32_bf16(qf, kfA, z, 0, 0, 0);
        f32x4 sB = __builtin_amdgcn_mfma_f32_16x16x32_bf16(qf, kfB, z, 0, 0, 0);
#pragma unroll
        for (int r = 0; r < 4; ++r) {
            csA += exp2f(sA[r]);
            csB += (4 * g + r >= c) ? exp2f(sB[r]) : 0.f;
        }
    }
    for (int q0 = k0 + 32; q0 < T_SEQ; q0 += 16) {   // both tiles full
        bf16x8 qf = {0, 0, 0, 0, 0, 0, 0, 0};
        if (g < 2) qf = *(const bf16x8*)(Qh + (size_t)(hbT + q0 + c) * 16 + 8 * g);
        f32x4 sA = __builtin_amdgcn_mfma_f32_16x16x32_bf16(qf, kfA, z, 0, 0, 0);
        f32x4 sB = __builtin_amdgcn_mfma_f32_16x16x32_bf16(qf, kfB, z, 0, 0, 0);
#pragma unroll
        for (int r = 0; r < 4; ++r) {
            csA += exp2f(sA[r]);
            csB += exp2f(sB[r]);
        }
    }
    csA += __shfl_xor(csA, 16);
    csA += __shfl_xor(csA, 32);
    csB += __shfl_xor(csB, 16);
    csB += __shfl_xor(csB, 32);

    // lanes 0..15 hold inv for k0+c; lanes 16..31 (g=1) hold inv for k0+16+c
    if (lane < 32) invl[wave][lane] = 1.0f / ((lane < 16) ? csA : csB);

    // scale V columns [k0, k0+32): lane -> (e = lane>>2, 8-k chunk)
    int e = lane >> 2, kk = (lane & 3) * 8;
    size_t vo = (size_t)(hb * 16 + e) * T_SEQ + k0 + kk;
    bf16x8 v = *(bf16x8*)(Vs + vo);
    f32x4 i0 = *(f32x4*)&invl[wave][kk];
    f32x4 i1 = *(f32x4*)&invl[wave][kk + 4];
    bf16x8 o;
#pragma unroll
    for (int j = 0; j < 4; ++j) o[j] = f2bf(bf2f(v[j]) * i0[j]);
#pragma unroll
    for (int j = 0; j < 4; ++j) o[4 + j] = f2bf(bf2f(v[4 + j]) * i1[j]);
    *(bf16x8*)(Vs + vo) = o;
}

// ---------------------------------------------------------------------------
// K3: attention output. Wave-independent: each wave owns 32 q-rows (2 Q-frags
// in regs), streams K/V frags from L2, no LDS, no barriers.
// O[q] = sum_{k<=q} exp2(S') * Vs   (V pre-scaled by invc)
// grid (16, 32 hb), block 256 = 4 waves; q0 = (63 - (bx*4+wave))*32
// (s=0 is the longest -> dispatched first)
// ---------------------------------------------------------------------------
__global__ __launch_bounds__(256) void k_attn(const short* __restrict__ Qh,
                                              const short* __restrict__ Kh,
                                              const short* __restrict__ Vs,
                                              short* __restrict__ AObf) {
    int hb = blockIdx.y, h = hb >> 2, b = hb & 3;
    int wave = threadIdx.x >> 6, lane = threadIdx.x & 63;
    int g = lane >> 4, c = lane & 15;
    int s = blockIdx.x * 4 + wave;
    int q0 = (63 - s) * 32;
    const int hbT = hb * T_SEQ;
    const f32x4 z = {0.f, 0.f, 0.f, 0.f};

    bf16x8 qf0 = {0, 0, 0, 0, 0, 0, 0, 0};
    bf16x8 qf1 = {0, 0, 0, 0, 0, 0, 0, 0};
    if (g < 2) {
        qf0 = *(const bf16x8*)(Qh + (size_t)(hbT + q0 + c) * 16 + 8 * g);
        qf1 = *(const bf16x8*)(Qh + (size_t)(hbT + q0 + 16 + c) * 16 + 8 * g);
    }
    const short* vb = Vs + (size_t)(hb * 16 + c) * T_SEQ;

    f32x4 acc0 = {0.f, 0.f, 0.f, 0.f};
    f32x4 acc1 = {0.f, 0.f, 0.f, 0.f};

    for (int k0 = 0; k0 < q0; k0 += 32) {            // full tiles, no masking
        bf16x8 kf0 = {0, 0, 0, 0, 0, 0, 0, 0};
        bf16x8 kf1 = {0, 0, 0, 0, 0, 0, 0, 0};
        if (g < 2) {
            kf0 = *(const bf16x8*)(Kh + (size_t)(hbT + k0 + c) * 16 + 8 * g);
            kf1 = *(const bf16x8*)(Kh + (size_t)(hbT + k0 + 16 + c) * 16 + 8 * g);
        }
        bf16x4 v0 = *(const bf16x4*)(vb + k0 + 4 * g);
        bf16x4 v1 = *(const bf16x4*)(vb + k0 + 16 + 4 * g);

        f32x4 sA0 = __builtin_amdgcn_mfma_f32_16x16x32_bf16(kf0, qf0, z, 0, 0, 0);
        f32x4 sA1 = __builtin_amdgcn_mfma_f32_16x16x32_bf16(kf1, qf0, z, 0, 0, 0);
        f32x4 sB0 = __builtin_amdgcn_mfma_f32_16x16x32_bf16(kf0, qf1, z, 0, 0, 0);
        f32x4 sB1 = __builtin_amdgcn_mfma_f32_16x16x32_bf16(kf1, qf1, z, 0, 0, 0);

        bf16x8 vf;
#pragma unroll
        for (int t = 0; t < 4; ++t) { vf[t] = v0[t]; vf[4 + t] = v1[t]; }

        bf16x8 aA, aB;
#pragma unroll
        for (int t = 0; t < 4; ++t) {
            aA[t] = bftrunc(exp2f(sA0[t]));
            aA[4 + t] = bftrunc(exp2f(sA1[t]));
            aB[t] = bftrunc(exp2f(sB0[t]));
            aB[4 + t] = bftrunc(exp2f(sB1[t]));
        }
        acc0 = __builtin_amdgcn_mfma_f32_16x16x32_bf16(aA, vf, acc0, 0, 0, 0);
        acc1 = __builtin_amdgcn_mfma_f32_16x16x32_bf16(aB, vf, acc1, 0, 0, 0);
    }

    {   // diagonal block k0 = q0
        int k0 = q0;
        bf16x8 kf0 = {0, 0, 0, 0, 0, 0, 0, 0};
        bf16x8 kf1 = {0, 0, 0, 0, 0, 0, 0, 0};
        if (g < 2) {
            kf0 = *(const bf16x8*)(Kh + (size_t)(hbT + k0 + c) * 16 + 8 * g);
            kf1 = *(const bf16x8*)(Kh + (size_t)(hbT + k0 + 16 + c) * 16 + 8 * g);
        }
        bf16x4 v0 = *(const bf16x4*)(vb + k0 + 4 * g);
        bf16x4 v1 = *(const bf16x4*)(vb + k0 + 16 + 4 * g);

        // subtile0 (q rows q0..q0+15): kf0 diagonal, kf1 fully masked
        f32x4 sA0 = __builtin_amdgcn_mfma_f32_16x16x32_bf16(kf0, qf0, z, 0, 0, 0);
        // subtile1 (q rows q0+16..q0+31): kf0 full, kf1 diagonal
        f32x4 sB0 = __builtin_amdgcn_mfma_f32_16x16x32_bf16(kf0, qf1, z, 0, 0, 0);
        f32x4 sB1 = __builtin_amdgcn_mfma_f32_16x16x32_bf16(kf1, qf1, z, 0, 0, 0);

        bf16x8 vf;
#pragma unroll
        for (int t = 0; t < 4; ++t) { vf[t] = v0[t]; vf[4 + t] = v1[t]; }

        bf16x8 aA, aB;
#pragma unroll
        for (int t = 0; t < 4; ++t) {
            aA[t] = (4 * g + t <= c) ? bftrunc(exp2f(sA0[t])) : (short)0;
            aA[4 + t] = (short)0;
            aB[t] = bftrunc(exp2f(sB0[t]));
            aB[4 + t] = (4 * g + t <= c) ? bftrunc(exp2f(sB1[t])) : (short)0;
        }
        acc0 = __builtin_amdgcn_mfma_f32_16x16x32_bf16(aA, vf, acc0, 0, 0, 0);
        acc1 = __builtin_amdgcn_mfma_f32_16x16x32_bf16(aB, vf, acc1, 0, 0, 0);
    }

#pragma unroll
    for (int r = 0; r < 4; ++r) {
        AObf[(size_t)(b * T_SEQ + q0 + 4 * g + r) * DMODEL + h * EHEAD + c] = f2bf(acc0[r]);
        AObf[(size_t)(b * T_SEQ + q0 + 16 + 4 * g + r) * DMODEL + h * EHEAD + c] = f2bf(acc1[r]);
    }
}

// ---------------------------------------------------------------------------
// K4: ff1 = relu(AO @ W1 + b1) -> F bf16 [8192][512]. W1t[n][k] in registers.
// block 256 (4 waves x 16 rows), grid (128 rowstrips, 4 colchunks)
// ---------------------------------------------------------------------------
__global__ __launch_bounds__(256) void k_ff1(const short* __restrict__ AObf,
                                             const short* __restrict__ W1t,
                                             const float* __restrict__ b1,
                                             short* __restrict__ F) {
    int nc = blockIdx.y;
    int wave = threadIdx.x >> 6, lane = threadIdx.x & 63;
    int g = lane >> 4, c = lane & 15;
    int row0 = blockIdx.x * 64 + wave * 16;

    bf16x8 wf[8][4];
#pragma unroll
    for (int nt = 0; nt < 8; ++nt)
#pragma unroll
        for (int kk = 0; kk < 4; ++kk)
            wf[nt][kk] = *(const bf16x8*)(W1t + (nc * 128 + nt * 16 + c) * 128 + kk * 32 + 8 * g);

    bf16x8 af[4];
#pragma unroll
    for (int kk = 0; kk < 4; ++kk)
        af[kk] = *(const bf16x8*)(AObf + (size_t)(row0 + c) * 128 + kk * 32 + 8 * g);

    f32x4 acc[8];
#pragma unroll
    for (int nt = 0; nt < 8; ++nt) acc[nt] = (f32x4){0.f, 0.f, 0.f, 0.f};
#pragma unroll
    for (int kk = 0; kk < 4; ++kk)
#pragma unroll
        for (int nt = 0; nt < 8; ++nt)
            acc[nt] = __builtin_amdgcn_mfma_f32_16x16x32_bf16(af[kk], wf[nt][kk], acc[nt], 0, 0, 0);

#pragma unroll
    for (int nt = 0; nt < 8; ++nt) {
        int col = nc * 128 + nt * 16 + c;
        float bb = b1[col];
#pragma unroll
        for (int r = 0; r < 4; ++r)
            F[(size_t)(row0 + 4 * g + r) * DFF + col] = f2bf(fmaxf(acc[nt][r] + bb, 0.f));
    }
}

// ---------------------------------------------------------------------------
// K5: out = F @ W2 + b2 + xpe. W2t[n][k=512] in registers (32-col groups).
// block 256 (4 waves x 16 rows), grid (128 rowstrips, 4 colgroups)
// ---------------------------------------------------------------------------
__global__ __launch_bounds__(256) void k_ff2(const short* __restrict__ F,
                                             const short* __restrict__ W2t,
                                             const float* __restrict__ b2,
                                             const float* __restrict__ xpe,
                                             float* __restrict__ out) {
    int ng = blockIdx.y;
    int wave = threadIdx.x >> 6, lane = threadIdx.x & 63;
    int g = lane >> 4, c = lane & 15;
    int row0 = blockIdx.x * 64 + wave * 16;

    bf16x8 wf[2][16];
#pragma unroll
    for (int nt = 0; nt < 2; ++nt)
#pragma unroll
        for (int kk = 0; kk < 16; ++kk)
            wf[nt][kk] = *(const bf16x8*)(W2t + (ng * 32 + nt * 16 + c) * 512 + kk * 32 + 8 * g);

    f32x4 acc[2];
    acc[0] = (f32x4){0.f, 0.f, 0.f, 0.f};
    acc[1] = (f32x4){0.f, 0.f, 0.f, 0.f};
#pragma unroll
    for (int kk = 0; kk < 16; ++kk) {
        bf16x8 a = *(const bf16x8*)(F + (size_t)(row0 + c) * 512 + kk * 32 + 8 * g);
        acc[0] = __builtin_amdgcn_mfma_f32_16x16x32_bf16(a, wf[0][kk], acc[0], 0, 0, 0);
        acc[1] = __builtin_amdgcn_mfma_f32_16x16x32_bf16(a, wf[1][kk], acc[1], 0, 0, 0);
    }
#pragma unroll
    for (int nt = 0; nt < 2; ++nt) {
        int col = ng * 32 + nt * 16 + c;
        float bb = b2[col];
#pragma unroll
        for (int r = 0; r < 4; ++r) {
            size_t o = (size_t)(row0 + 4 * g + r) * DMODEL + col;
            out[o] = acc[nt][r] + bb + xpe[o];
        }
    }
}

// ---------------------------------------------------------------------------
extern "C" void kernel_launch(void* const* d_in, const int* in_sizes, int n_in,
                              void* d_out, int out_size, void* d_ws, size_t ws_size,
                              hipStream_t stream) {
    const float* x  = (const float*)d_in[0];
    const float* WQ = (const float*)d_in[1];
    const float* WK = (const float*)d_in[2];
    const float* WV = (const float*)d_in[3];
    const float* W1 = (const float*)d_in[4];
    const float* b1 = (const float*)d_in[5];
    const float* W2 = (const float*)d_in[6];
    const float* b2 = (const float*)d_in[7];
    float* out = (float*)d_out;

    const size_t NTD = (size_t)BATCH * T_SEQ * DMODEL;   // 1048576
    float* xpe   = (float*)d_ws;
    short* sbase = (short*)(xpe + NTD);
    short* xpe16 = sbase;
    short* Qh    = xpe16 + NTD;
    short* Kh    = Qh + NTD;
    short* Vs    = Kh + NTD;
    short* AObf  = Vs + NTD;
    short* F     = AObf + NTD;            // 8192*512 = 4*NTD shorts
    short* Wqkvt = F + 4 * NTD;
    short* W1t   = Wqkvt + 3 * 16384;
    short* W2t   = W1t + 65536;

    k_pre<<<dim3(4800), dim3(256), 0, stream>>>(x, WQ, WK, WV, W1, W2,
                                                xpe, xpe16, Wqkvt, W1t, W2t);

    k_qkv<<<dim3(128, 3), dim3(256), 0, stream>>>(xpe16, Wqkvt, Qh, Kh, Vs);

    k_colsum<<<dim3(16, 32), dim3(256), 0, stream>>>(Qh, Kh, Vs);

    k_attn<<<dim3(16, 32), dim3(256), 0, stream>>>(Qh, Kh, Vs, AObf);

    k_ff1<<<dim3(128, 4), dim3(256), 0, stream>>>(AObf, W1t, b1, F);

    k_ff2<<<dim3(128, 4), dim3(256), 0, stream>>>(F, W2t, b2, xpe, out);
}